// Round 2
// baseline (3938.974 us; speedup 1.0000x reference)
//
#include <hip/hip_runtime.h>
#include <math.h>

typedef unsigned short u16;
typedef __attribute__((ext_vector_type(8))) __bf16 bf16x8;
typedef __attribute__((ext_vector_type(4))) float f32x4;

__device__ inline u16 f2bf(float x) {
  union { float f; unsigned u; } v; v.f = x;
  unsigned r = v.u + 0x7fffu + ((v.u >> 16) & 1u);
  return (u16)(r >> 16);
}

__device__ inline void gl_lds16(const void* g, void* s) {
  __builtin_amdgcn_global_load_lds(
      (__attribute__((address_space(1))) void*)g,
      (__attribute__((address_space(3))) void*)s, 16, 0, 0);
}

// ---------------------------------------------------------------------------
// Transpose + f32->bf16 convert: in[R][C] f32 -> out[C][R] bf16
// ---------------------------------------------------------------------------
__global__ void transpose_cvt(const float* __restrict__ in, u16* __restrict__ out,
                              int R, int C)
{
  __shared__ float tile[32][33];
  const int c0 = blockIdx.x * 32, r0 = blockIdx.y * 32;
  const int tx = threadIdx.x, ty = threadIdx.y;
#pragma unroll
  for (int j = 0; j < 32; j += 8)
    tile[ty + j][tx] = in[(size_t)(r0 + ty + j) * C + c0 + tx];
  __syncthreads();
#pragma unroll
  for (int j = 0; j < 32; j += 8)
    out[(size_t)(c0 + ty + j) * R + r0 + tx] = f2bf(tile[tx][ty + j]);
}

// ---------------------------------------------------------------------------
// Embedding: x[b,t,:] = tok_emb[idx[b,t],:] + pos_emb[t,:]   (f32)
// grid = B*T*D/4/256 = 4096 blocks, one float4 per thread.
// ---------------------------------------------------------------------------
__global__ __launch_bounds__(256) void embed_kernel(
    const int* __restrict__ idx, const float* __restrict__ tok,
    const float* __restrict__ pos, float* __restrict__ x)
{
  const int gid = blockIdx.x * 256 + threadIdx.x;   // one float4 each
  const int d4 = gid & 255;                          // D/4 = 256
  const int r  = gid >> 8;                           // row = b*T + t, < 4096
  const int t  = r & 1023;
  const int token = idx[r];
  float4 a = ((const float4*)(tok + (size_t)token * 1024))[d4];
  float4 p = ((const float4*)(pos + (size_t)t * 1024))[d4];
  a.x += p.x; a.y += p.y; a.z += p.z; a.w += p.w;
  ((float4*)(x + (size_t)r * 1024))[d4] = a;
}

// ---------------------------------------------------------------------------
// LayerNorm f32 [rows,1024] -> bf16 out (one block per row)
// ---------------------------------------------------------------------------
__global__ __launch_bounds__(256) void ln_kernel(
    const float* __restrict__ x, const float* __restrict__ g,
    const float* __restrict__ bta, u16* __restrict__ out)
{
  __shared__ float red[8];
  const int row = blockIdx.x, tid = threadIdx.x;
  const int lane = tid & 63, w = tid >> 6;
  const float4 v = ((const float4*)(x + (size_t)row * 1024))[tid];
  float s  = v.x + v.y + v.z + v.w;
  float s2 = v.x * v.x + v.y * v.y + v.z * v.z + v.w * v.w;
#pragma unroll
  for (int d = 1; d < 64; d <<= 1) { s += __shfl_xor(s, d); s2 += __shfl_xor(s2, d); }
  if (lane == 0) { red[w] = s; red[4 + w] = s2; }
  __syncthreads();
  s  = red[0] + red[1] + red[2] + red[3];
  s2 = red[4] + red[5] + red[6] + red[7];
  const float mean = s * (1.0f / 1024.0f);
  const float var  = s2 * (1.0f / 1024.0f) - mean * mean;
  const float rs   = rsqrtf(var + 1e-5f);
  const float4 gg = ((const float4*)g)[tid];
  const float4 bb = ((const float4*)bta)[tid];
  ushort4 o;
  o.x = f2bf((v.x - mean) * rs * gg.x + bb.x);
  o.y = f2bf((v.y - mean) * rs * gg.y + bb.y);
  o.z = f2bf((v.z - mean) * rs * gg.z + bb.z);
  o.w = f2bf((v.w - mean) * rs * gg.w + bb.w);
  ((ushort4*)(out + (size_t)row * 1024))[tid] = o;
}

// ---------------------------------------------------------------------------
// GEMM: C[M,N] = A[M,K](bf16) @ Bt[N,K](bf16)^T, m97-style 128x128x32 tile.
// EPI 1: f32 out = acc + bias[n] + resid (in-place x)
// EPI 2: bias+GELU -> bf16 3: bias -> f32 (head)
// EPI 4: fused qkv: n<1024 -> q bf16; <2048 -> k bf16; else v transposed [B,D,T]
// ---------------------------------------------------------------------------
template <int EPI>
__global__ __launch_bounds__(256) void gemm_bt(
    const u16* __restrict__ A, const u16* __restrict__ Bt,
    const float* __restrict__ bias, const float* __restrict__ resid,
    float* __restrict__ outf, u16* __restrict__ outq,
    u16* __restrict__ outk, u16* __restrict__ outv,
    int M, int N, int K)
{
  __shared__ u16 lA[128 * 32];
  __shared__ u16 lB[128 * 32];
  const int tid = threadIdx.x;
  const int lane = tid & 63, w = tid >> 6;
  const int wr = w >> 1, wc = w & 1;
  const int m0 = blockIdx.y * 128, n0 = blockIdx.x * 128;
  const u16* Ab = A + (size_t)m0 * K;
  const u16* Bb = Bt + (size_t)n0 * K;

  f32x4 acc[4][4];
#pragma unroll
  for (int i = 0; i < 4; i++)
#pragma unroll
    for (int j = 0; j < 4; j++) acc[i][j] = (f32x4){0.f, 0.f, 0.f, 0.f};

  const int c0 = tid, c1 = tid + 256;
  const int r0 = c0 >> 2, o0 = (c0 & 3) * 8;
  const int r1 = c1 >> 2, o1 = (c1 & 3) * 8;

  for (int k0 = 0; k0 < K; k0 += 32) {
    __syncthreads();
    gl_lds16(Ab + (size_t)r0 * K + k0 + o0, &lA[c0 * 8]);
    gl_lds16(Ab + (size_t)r1 * K + k0 + o1, &lA[c1 * 8]);
    gl_lds16(Bb + (size_t)r0 * K + k0 + o0, &lB[c0 * 8]);
    gl_lds16(Bb + (size_t)r1 * K + k0 + o1, &lB[c1 * 8]);
    __syncthreads();
    bf16x8 af[4], bfv[4];
#pragma unroll
    for (int mi = 0; mi < 4; mi++)
      af[mi] = *(const bf16x8*)&lA[(wr * 64 + mi * 16 + (lane & 15)) * 32 + (lane >> 4) * 8];
#pragma unroll
    for (int ni = 0; ni < 4; ni++)
      bfv[ni] = *(const bf16x8*)&lB[(wc * 64 + ni * 16 + (lane & 15)) * 32 + (lane >> 4) * 8];
#pragma unroll
    for (int mi = 0; mi < 4; mi++)
#pragma unroll
      for (int ni = 0; ni < 4; ni++)
        acc[mi][ni] = __builtin_amdgcn_mfma_f32_16x16x32_bf16(af[mi], bfv[ni], acc[mi][ni], 0, 0, 0);
  }

#pragma unroll
  for (int mi = 0; mi < 4; mi++) {
#pragma unroll
    for (int ni = 0; ni < 4; ni++) {
#pragma unroll
      for (int i = 0; i < 4; i++) {
        const int row = m0 + wr * 64 + mi * 16 + ((lane >> 4) << 2) + i;
        const int col = n0 + wc * 64 + ni * 16 + (lane & 15);
        const float v = acc[mi][ni][i];
        if (EPI == 1) {
          const size_t o = (size_t)row * N + col;
          outf[o] = resid[o] + bias[col] + v;
        } else if (EPI == 2) {
          const float t = v + bias[col];
          const float gl = 0.5f * t * (1.0f + erff(t * 0.70710678118654752f));
          outq[(size_t)row * N + col] = f2bf(gl);
        } else if (EPI == 3) {
          outf[(size_t)row * N + col] = v + bias[col];
        } else {  // 4: fused qkv
          const int which = col >> 10, cn = col & 1023;
          if (which == 0)      outq[(size_t)row * 1024 + cn] = f2bf(v);
          else if (which == 1) outk[(size_t)row * 1024 + cn] = f2bf(v);
          else {
            const int b = row >> 10, t = row & 1023;
            outv[((size_t)b * 1024 + cn) * 1024 + t] = f2bf(v);  // vT[b][d][t]
          }
        }
      }
    }
  }
}

// ---------------------------------------------------------------------------
// Flash attention (causal), bf16 MFMA. 1 wave = 16 q-rows; k-tile = 32.
// q,k: [B*T, D] bf16; vT: [B, D, T] bf16; y out: [B*T, D] bf16.
// Wave pairing (p, 63-p) balances causal work.
// ---------------------------------------------------------------------------
__global__ __launch_bounds__(256) void attn_kernel(
    const u16* __restrict__ qb, const u16* __restrict__ kb,
    const u16* __restrict__ vt, u16* __restrict__ yb)
{
  __shared__ u16 pl_all[4][16 * 32];
  const int tid = threadIdx.x;
  const int lane = tid & 63, w = tid >> 6;
  u16* pl = pl_all[w];
  const int gw = blockIdx.x * 4 + w;
  const int pr = gw & 31, bh = gw >> 5;
  const int b = bh >> 4, h = bh & 15;
  const int c16 = lane & 15, g8 = (lane >> 4) * 8, g4 = (lane >> 4) * 4;
  const size_t bT = (size_t)b * 1024;
  const int hd0 = h * 64;
  const float scale = 0.125f;

  for (int half = 0; half < 2; ++half) {
    const int qt = half ? (63 - pr) : pr;
    const int q0 = qt * 16;
    bf16x8 qf0, qf1;
    {
      const u16* qp = qb + (bT + q0 + c16) * 1024 + hd0 + g8;
      qf0 = *(const bf16x8*)qp;
      qf1 = *(const bf16x8*)(qp + 32);
    }
    float m_[4], l_[4];
    f32x4 O[4];
#pragma unroll
    for (int i = 0; i < 4; i++) { m_[i] = -INFINITY; l_[i] = 0.f; }
#pragma unroll
    for (int nb = 0; nb < 4; nb++) O[nb] = (f32x4){0.f, 0.f, 0.f, 0.f};

    const int ktmax = (q0 + 15) >> 5;
    for (int kt = 0; kt <= ktmax; ++kt) {
      f32x4 sA = (f32x4){0.f, 0.f, 0.f, 0.f};
      f32x4 sB = (f32x4){0.f, 0.f, 0.f, 0.f};
      {
        const u16* kp = kb + (bT + kt * 32 + c16) * 1024 + hd0 + g8;
        const bf16x8 k00 = *(const bf16x8*)kp;
        const bf16x8 k01 = *(const bf16x8*)(kp + 32);
        const bf16x8 k10 = *(const bf16x8*)(kp + 16 * 1024);
        const bf16x8 k11 = *(const bf16x8*)(kp + 16 * 1024 + 32);
        sA = __builtin_amdgcn_mfma_f32_16x16x32_bf16(qf0, k00, sA, 0, 0, 0);
        sA = __builtin_amdgcn_mfma_f32_16x16x32_bf16(qf1, k01, sA, 0, 0, 0);
        sB = __builtin_amdgcn_mfma_f32_16x16x32_bf16(qf0, k10, sB, 0, 0, 0);
        sB = __builtin_amdgcn_mfma_f32_16x16x32_bf16(qf1, k11, sB, 0, 0, 0);
      }
      float alpha[4];
#pragma unroll
      for (int i = 0; i < 4; i++) {
        const int row = q0 + g4 + i;
        const int col0 = kt * 32 + c16;
        float s0v = (col0 <= row) ? sA[i] * scale : -INFINITY;
        float s1v = (col0 + 16 <= row) ? sB[i] * scale : -INFINITY;
        float t = fmaxf(s0v, s1v);
        t = fmaxf(t, __shfl_xor(t, 1));
        t = fmaxf(t, __shfl_xor(t, 2));
        t = fmaxf(t, __shfl_xor(t, 4));
        t = fmaxf(t, __shfl_xor(t, 8));
        const float mn = fmaxf(m_[i], t);
        const float al = __expf(m_[i] - mn);
        const float p0 = __expf(s0v - mn);
        const float p1 = __expf(s1v - mn);
        float ps = p0 + p1;
        ps += __shfl_xor(ps, 1);
        ps += __shfl_xor(ps, 2);
        ps += __shfl_xor(ps, 4);
        ps += __shfl_xor(ps, 8);
        l_[i] = l_[i] * al + ps;
        m_[i] = mn; alpha[i] = al;
        pl[(g4 + i) * 32 + c16] = f2bf(p0);
        pl[(g4 + i) * 32 + c16 + 16] = f2bf(p1);
      }
      asm volatile("s_waitcnt lgkmcnt(0)" ::: "memory");
      const bf16x8 pf = *(const bf16x8*)&pl[c16 * 32 + g8];
#pragma unroll
      for (int nb = 0; nb < 4; nb++) {
        const u16* vp = vt + ((size_t)b * 1024 + hd0 + nb * 16 + c16) * 1024 + kt * 32 + g8;
        const bf16x8 vf = *(const bf16x8*)vp;
        f32x4 o = O[nb];
#pragma unroll
        for (int i = 0; i < 4; i++) o[i] *= alpha[i];
        O[nb] = __builtin_amdgcn_mfma_f32_16x16x32_bf16(pf, vf, o, 0, 0, 0);
      }
    }
#pragma unroll
    for (int nb = 0; nb < 4; nb++)
#pragma unroll
      for (int i = 0; i < 4; i++) {
        const int row = q0 + g4 + i;
        yb[(bT + row) * 1024 + hd0 + nb * 16 + c16] = f2bf(O[nb][i] / l_[i]);
      }
  }
}

// ---------------------------------------------------------------------------
// Workspace layout (total 112 MiB):
//   x:    f32 @ 0           16,777,216 B
//   hbuf: u16 @ 16,777,216   8,388,608 B
//   qb:   u16 @ 25,165,824   8,388,608 B   <- whT aliases from here at the end
//   kbuf: u16 @ 33,554,432   8,388,608 B
//   vt:   u16 @ 41,943,040   8,388,608 B
//   yb:   u16 @ 50,331,648   8,388,608 B
//   ub:   u16 @ 58,720,256  33,554,432 B
//   wlT:  u16 @ 92,274,688  25,165,824 B  [qkvT 3M | woT 1M | w1T 4M | w2T 4M elems]
//   whT needs 65,536,000 B @ qb (25,165,824 .. 90,701,824) -- fits before wlT.
// ---------------------------------------------------------------------------
extern "C" void kernel_launch(void* const* d_in, const int* in_sizes, int n_in,
                              void* d_out, int out_size, void* d_ws, size_t ws_size,
                              hipStream_t stream)
{
  const int*   idx  = (const int*)d_in[0];
  const float* tok  = (const float*)d_in[1];
  const float* pos  = (const float*)d_in[2];
  const float* wq   = (const float*)d_in[3];
  const float* wk   = (const float*)d_in[4];
  const float* wv   = (const float*)d_in[5];
  const float* wo   = (const float*)d_in[6];
  const float* bo   = (const float*)d_in[7];
  const float* ln1g = (const float*)d_in[8];
  const float* ln1b = (const float*)d_in[9];
  const float* ln2g = (const float*)d_in[10];
  const float* ln2b = (const float*)d_in[11];
  const float* w1   = (const float*)d_in[12];
  const float* b1   = (const float*)d_in[13];
  const float* w2   = (const float*)d_in[14];
  const float* b2   = (const float*)d_in[15];
  const float* lnfg = (const float*)d_in[16];
  const float* lnfb = (const float*)d_in[17];
  const float* wh   = (const float*)d_in[18];
  const float* bh   = (const float*)d_in[19];
  float* out = (float*)d_out;

  char* ws = (char*)d_ws;
  float* x  = (float*)ws;
  u16* hbuf = (u16*)(ws + 16777216);
  u16* qb   = hbuf + 4194304;
  u16* kbuf = qb + 4194304;
  u16* vt   = kbuf + 4194304;
  u16* yb   = vt + 4194304;
  u16* ub   = yb + 4194304;
  u16* wlT  = ub + 16777216;            // per-layer transposed weights
  u16* qkvT = wlT;                      // [3072,1024]
  u16* woT  = wlT + 3145728;            // [1024,1024]
  u16* w1T  = woT + 1048576;            // [4096,1024]
  u16* w2T  = w1T + 4194304;            // [1024,4096]
  u16* whT  = qb;                       // [32000,1024] aliases dead act buffers

  dim3 tb(32, 8);
  embed_kernel<<<4096, 256, 0, stream>>>(idx, tok, pos, x);

  for (int l = 0; l < 8; ++l) {
    const size_t lw = (size_t)l * 1048576;
    transpose_cvt<<<dim3(32, 32),  tb, 0, stream>>>(wq + lw, qkvT,           1024, 1024);
    transpose_cvt<<<dim3(32, 32),  tb, 0, stream>>>(wk + lw, qkvT + 1048576, 1024, 1024);
    transpose_cvt<<<dim3(32, 32),  tb, 0, stream>>>(wv + lw, qkvT + 2097152, 1024, 1024);
    transpose_cvt<<<dim3(32, 32),  tb, 0, stream>>>(wo + lw, woT,            1024, 1024);
    transpose_cvt<<<dim3(128, 32), tb, 0, stream>>>(w1 + (size_t)l * 4194304, w1T, 1024, 4096);
    transpose_cvt<<<dim3(32, 128), tb, 0, stream>>>(w2 + (size_t)l * 4194304, w2T, 4096, 1024);

    ln_kernel<<<4096, 256, 0, stream>>>(x, ln1g + l * 1024, ln1b + l * 1024, hbuf);
    gemm_bt<4><<<dim3(24, 32), 256, 0, stream>>>(hbuf, qkvT,
        nullptr, nullptr, nullptr, qb, kbuf, vt, 4096, 3072, 1024);
    attn_kernel<<<512, 256, 0, stream>>>(qb, kbuf, vt, yb);
    gemm_bt<1><<<dim3(8, 32), 256, 0, stream>>>(yb, woT,
        bo + l * 1024, x, x, nullptr, nullptr, nullptr, 4096, 1024, 1024);
    ln_kernel<<<4096, 256, 0, stream>>>(x, ln2g + l * 1024, ln2b + l * 1024, hbuf);
    gemm_bt<2><<<dim3(32, 32), 256, 0, stream>>>(hbuf, w1T,
        b1 + l * 4096, nullptr, nullptr, ub, nullptr, nullptr, 4096, 4096, 1024);
    gemm_bt<1><<<dim3(8, 32), 256, 0, stream>>>(ub, w2T,
        b2 + l * 1024, x, x, nullptr, nullptr, nullptr, 4096, 1024, 4096);
  }
  ln_kernel<<<4096, 256, 0, stream>>>(x, lnfg, lnfb, hbuf);
  transpose_cvt<<<dim3(1000, 32), tb, 0, stream>>>(wh, whT, 1024, 32000);
  gemm_bt<3><<<dim3(250, 32), 256, 0, stream>>>(hbuf, whT, bh,
      nullptr, out, nullptr, nullptr, nullptr, 4096, 32000, 1024);
}